// Round 1
// baseline (144.591 us; speedup 1.0000x reference)
//
#include <hip/hip_runtime.h>

// B=4, S=512, D=256, UNITS=128.  out: [B,S,D] fp32.
#define SEQ 512
#define DIM 256
#define UN  128
#define BS  2048   // B*S
#define TR  8      // rows per proj block

// ---------------- Kernel 1: Q = values@Wq, Vt = (values@Wv)^T ----------------
// grid BS/TR blocks x 256 thr. threads 0..127 -> Q column u, 128..255 -> V column u.
// values[(r0+k)*DIM+d] is wave-uniform -> compiler scalarizes to s_load (K$),
// W[d*UN+u] coalesces across the 128-thread half.
__global__ __launch_bounds__(256) void proj_kernel(
    const float* __restrict__ values, const float* __restrict__ Wq,
    const float* __restrict__ Wv, float* __restrict__ Qb, float* __restrict__ Vt) {
  const int t = threadIdx.x;
  const int r0 = blockIdx.x * TR;
  const int half = t >> 7;
  const int u = t & 127;
  const float* __restrict__ W = half ? Wv : Wq;
  float acc[TR];
#pragma unroll
  for (int k = 0; k < TR; ++k) acc[k] = 0.f;
#pragma unroll 4
  for (int d = 0; d < DIM; ++d) {
    const float w = W[d * UN + u];
#pragma unroll
    for (int k = 0; k < TR; ++k)
      acc[k] = fmaf(values[(r0 + k) * DIM + d], w, acc[k]);
  }
  if (half == 0) {
#pragma unroll
    for (int k = 0; k < TR; ++k) Qb[(r0 + k) * UN + u] = acc[k];   // coalesced per k
  } else {
    // Vt layout [UN][BS]; per-thread 8 consecutive floats (2x float4 stores)
#pragma unroll
    for (int k = 0; k < TR; ++k) Vt[u * BS + r0 + k] = acc[k];
  }
}

// ---------------- Kernel 2: per (b,i): scores -> softmax -> context ----------
__global__ __launch_bounds__(256) void attn_kernel(
    const float* __restrict__ values, const float* __restrict__ Qb,
    const float* __restrict__ Vt, const float* __restrict__ Vw,
    float* __restrict__ out) {
  __shared__ float sc[SEQ];       // scores -> probs
  __shared__ float red[256];      // block reductions
  __shared__ float ctxp[4 * DIM]; // context partials (one per wave-group)

  const int t = threadIdx.x;
  const int r = blockIdx.x;      // b*S + i
  const int b = r >> 9;
  const int i = r & (SEQ - 1);
  const int bS = b * SEQ;

  // ---- scores: thread t handles j = jt*256 + t, j <= i (causal) ----
  const float* __restrict__ qrow = Qb + r * UN;   // uniform reads -> s_load
  for (int jt = 0; jt * 256 <= i; ++jt) {
    const int j = jt * 256 + t;
    if (j <= i) {
      const float* __restrict__ vp = Vt + bS + j; // stride-BS over u, coalesced over t
      float s = 0.f;
#pragma unroll 8
      for (int u = 0; u < UN; ++u) {
        const float x0 = qrow[u] + vp[u * BS];
        const float x  = fminf(fmaxf(x0, -15.f), 15.f);          // v_med3
        const float e  = __builtin_amdgcn_exp2f(x * 2.8853900817779268f); // e^(2x)
        const float th = (e - 1.f) * __builtin_amdgcn_rcpf(e + 1.f);      // tanh(x)
        s = fmaf(Vw[u], th, s);                                  // Vw uniform -> s_load
      }
      sc[j] = s;
    }
  }
  __syncthreads();

  // ---- softmax over sc[0..i]: max ----
  float m = -3.0e38f;
  for (int j = t; j <= i; j += 256) m = fmaxf(m, sc[j]);
  red[t] = m;
  __syncthreads();
#pragma unroll
  for (int sN = 128; sN > 0; sN >>= 1) {
    if (t < sN) red[t] = fmaxf(red[t], red[t + sN]);
    __syncthreads();
  }
  const float M = red[0];
  __syncthreads();

  // ---- exp + sum (normalization deferred to epilogue) ----
  float lsum = 0.f;
  for (int j = t; j <= i; j += 256) {
    const float p = __builtin_amdgcn_exp2f((sc[j] - M) * 1.4426950408889634f);
    sc[j] = p;
    lsum += p;
  }
  red[t] = lsum;
  __syncthreads();
#pragma unroll
  for (int sN = 128; sN > 0; sN >>= 1) {
    if (t < sN) red[t] += red[t + sN];
    __syncthreads();
  }
  const float inv = __builtin_amdgcn_rcpf(red[0]);

  // ---- context: wave-group g takes j ≡ g (mod 4); float4 over d ----
  const int g = t >> 6, l = t & 63;
  float4 acc = make_float4(0.f, 0.f, 0.f, 0.f);
  for (int j = g; j <= i; j += 4) {
    const float p = sc[j];
    const float4 v4 = *(const float4*)(values + (size_t)(bS + j) * DIM + l * 4);
    acc.x = fmaf(p, v4.x, acc.x);
    acc.y = fmaf(p, v4.y, acc.y);
    acc.z = fmaf(p, v4.z, acc.z);
    acc.w = fmaf(p, v4.w, acc.w);
  }
  *(float4*)&ctxp[g * DIM + l * 4] = acc;
  __syncthreads();
  const float o = (ctxp[t] + ctxp[DIM + t] + ctxp[2 * DIM + t] + ctxp[3 * DIM + t]) * inv;
  out[r * DIM + t] = o;
}

extern "C" void kernel_launch(void* const* d_in, const int* in_sizes, int n_in,
                              void* d_out, int out_size, void* d_ws, size_t ws_size,
                              hipStream_t stream) {
  const float* values = (const float*)d_in[0];
  const float* Wq     = (const float*)d_in[1];
  const float* Wv     = (const float*)d_in[2];
  const float* Vw     = (const float*)d_in[3];
  float* out = (float*)d_out;
  float* Qb  = (float*)d_ws;            // [BS][UN] = 1 MB
  float* Vt  = Qb + (size_t)BS * UN;    // [UN][BS] = 1 MB
  proj_kernel<<<dim3(BS / TR), 256, 0, stream>>>(values, Wq, Wv, Qb, Vt);
  attn_kernel<<<dim3(BS), 256, 0, stream>>>(values, Qb, Vt, Vw, out);
}

// Round 2
// 137.955 us; speedup vs baseline: 1.0481x; 1.0481x over previous
//
#include <hip/hip_runtime.h>

// B=4, S=512, D=256, UNITS=128. out: [B,S,D] fp32.
#define SEQ 512
#define DIM 256
#define UN  128
#define BSZ 2048                       // B*S
#define CSC 2.8853900817779268f        // 2*log2(e): folded into Qc/Vc so exp2(Qc+Vc)=e^{2(q+v)}

// ---------------- proj: Qc = c*(values@Wq) [BSZ][UN], Vc = c*(values@Wv)^T [UN][BSZ] ----
// 512 blocks x 256 thr, 4 rows/block. values rows staged in LDS (float4), read back as
// ds_read_b128 broadcast; W loads coalesced across the 128-thread half.
__global__ __launch_bounds__(256) void proj_kernel(
    const float* __restrict__ values, const float* __restrict__ Wq,
    const float* __restrict__ Wv, float* __restrict__ Qc, float* __restrict__ Vc) {
  __shared__ float vsm[4 * DIM];
  const int t = threadIdx.x;
  const int r0 = blockIdx.x * 4;
  {
    const int row = t >> 6, c4 = (t & 63) * 4;
    *(float4*)&vsm[row * DIM + c4] = *(const float4*)(values + (r0 + row) * DIM + c4);
  }
  __syncthreads();
  const int half = t >> 7, u = t & 127;
  const float* __restrict__ W = half ? Wv : Wq;
  float acc[4] = {0.f, 0.f, 0.f, 0.f};
  for (int d = 0; d < DIM; d += 4) {
    const float w0 = W[(d + 0) * UN + u], w1 = W[(d + 1) * UN + u];
    const float w2 = W[(d + 2) * UN + u], w3 = W[(d + 3) * UN + u];
#pragma unroll
    for (int k = 0; k < 4; ++k) {
      const float4 v = *(const float4*)&vsm[k * DIM + d];
      acc[k] = fmaf(v.x, w0, acc[k]);
      acc[k] = fmaf(v.y, w1, acc[k]);
      acc[k] = fmaf(v.z, w2, acc[k]);
      acc[k] = fmaf(v.w, w3, acc[k]);
    }
  }
  if (!half) {
#pragma unroll
    for (int k = 0; k < 4; ++k) Qc[(r0 + k) * UN + u] = acc[k] * CSC;  // coalesced
  } else {
    const float4 o = make_float4(acc[0] * CSC, acc[1] * CSC, acc[2] * CSC, acc[3] * CSC);
    *(float4*)(Vc + u * BSZ + r0) = o;  // r0 % 4 == 0 -> 16B aligned
  }
}

// ---------------- attn: block = (b, tile T) with rows {2T,2T+1, S-2-2T,S-1-2T} -------
// Work per block is constant: (2T+2) + (2S-2T) = 2S+2. Score = -2*sdot + const (dropped
// by softmax shift-invariance), sdot = sum_u Vw_u / (e^{2(q+v)}+1). Masked j -> 1e30
// sentinel -> p underflows to exactly 0.
__global__ __launch_bounds__(256) void attn_kernel(
    const float* __restrict__ values, const float* __restrict__ Qc,
    const float* __restrict__ Vc, const float* __restrict__ Vw,
    float* __restrict__ out) {
  __shared__ float sc[4 * SEQ];      // sdot, then p (unnormalized)
  __shared__ float part[16 * DIM];   // ctx partials: [4 j-groups][4 rows][DIM]
  __shared__ float invs[4];

  const int t = threadIdx.x;
  const int b = blockIdx.x >> 7, T = blockIdx.x & 127;
  const int bS = b * SEQ;
  const int il = 2 * T + 1;          // low-pair j max (= row l1)
  const int ih = SEQ - 1 - 2 * T;    // high-pair j max (= row h1), >= 257
  const int l0r = 2 * T, h0r = ih - 1;

  const float* __restrict__ ql0 = Qc + (bS + l0r) * UN;  // uniform -> s_load
  const float* __restrict__ ql1 = ql0 + UN;
  const float* __restrict__ qh0 = Qc + (bS + h0r) * UN;
  const float* __restrict__ qh1 = qh0 + UN;
  const float* __restrict__ vcb = Vc + bS;

  // ---- phase A: scores. High pair: thread t takes j = t (always) and t+256 if <= ih.
  for (int j = t; j <= ih; j += 256) {
    float s2 = 0.f, s3 = 0.f;
#pragma unroll 4
    for (int u = 0; u < UN; ++u) {
      const float vc = vcb[u * BSZ + j];                    // coalesced across t
      const float e2 = __builtin_amdgcn_exp2f(qh0[u] + vc); // inf-safe: rcp(inf)=0
      const float e3 = __builtin_amdgcn_exp2f(qh1[u] + vc);
      const float w = Vw[u];
      s2 = fmaf(w, __builtin_amdgcn_rcpf(e2 + 1.f), s2);
      s3 = fmaf(w, __builtin_amdgcn_rcpf(e3 + 1.f), s3);
    }
    sc[2 * SEQ + j] = (j <= h0r) ? s2 : 1e30f;
    sc[3 * SEQ + j] = s3;
  }
  // Low pair: mapped to HIGH thread ids (the ones that did only 1 high iter) -> balance.
  {
    const int off = 255 - il;  // il <= 255
    if (t >= off) {
      const int j = t - off;
      float s0 = 0.f, s1 = 0.f;
#pragma unroll 4
      for (int u = 0; u < UN; ++u) {
        const float vc = vcb[u * BSZ + j];
        const float e0 = __builtin_amdgcn_exp2f(ql0[u] + vc);
        const float e1 = __builtin_amdgcn_exp2f(ql1[u] + vc);
        const float w = Vw[u];
        s0 = fmaf(w, __builtin_amdgcn_rcpf(e0 + 1.f), s0);
        s1 = fmaf(w, __builtin_amdgcn_rcpf(e1 + 1.f), s1);
      }
      sc[0 * SEQ + j] = (j <= l0r) ? s0 : 1e30f;
      sc[1 * SEQ + j] = s1;
    }
  }
  __syncthreads();

  // ---- phase B: softmax, one wave per row, shuffle reductions, no barriers ----
  {
    const int w = t >> 6, l = t & 63;
    const int jmax = (w < 2) ? il : ih;   // pair range, so mask slots get p=0 written
    float m = 1e30f;
    for (int j = l; j <= jmax; j += 64) m = fminf(m, sc[w * SEQ + j]);
#pragma unroll
    for (int o = 32; o; o >>= 1) m = fminf(m, __shfl_xor(m, o));
    float sum = 0.f;
    for (int j = l; j <= jmax; j += 64) {
      const float p = __builtin_amdgcn_exp2f((m - sc[w * SEQ + j]) * CSC);
      sc[w * SEQ + j] = p;               // own row only -> no race
      sum += p;
    }
#pragma unroll
    for (int o = 32; o; o >>= 1) sum += __shfl_xor(sum, o);
    if (l == 0) invs[w] = __builtin_amdgcn_rcpf(sum);
  }
  __syncthreads();

  // ---- phase C: context. Wave g takes j === g (mod 4); values float4 shared by 4 rows.
  {
    const int g = t >> 6, d4 = (t & 63) * 4;
    float4 a0 = make_float4(0.f, 0.f, 0.f, 0.f), a1 = a0, a2 = a0, a3 = a0;
    for (int j = g; j <= il; j += 4) {
      const float p0 = sc[0 * SEQ + j], p1 = sc[1 * SEQ + j];  // LDS broadcast
      const float4 v = *(const float4*)(values + (bS + j) * DIM + d4);
      a0.x = fmaf(p0, v.x, a0.x); a0.y = fmaf(p0, v.y, a0.y);
      a0.z = fmaf(p0, v.z, a0.z); a0.w = fmaf(p0, v.w, a0.w);
      a1.x = fmaf(p1, v.x, a1.x); a1.y = fmaf(p1, v.y, a1.y);
      a1.z = fmaf(p1, v.z, a1.z); a1.w = fmaf(p1, v.w, a1.w);
    }
    for (int j = g; j <= ih; j += 4) {
      const float p2 = sc[2 * SEQ + j], p3 = sc[3 * SEQ + j];
      const float4 v = *(const float4*)(values + (bS + j) * DIM + d4);
      a2.x = fmaf(p2, v.x, a2.x); a2.y = fmaf(p2, v.y, a2.y);
      a2.z = fmaf(p2, v.z, a2.z); a2.w = fmaf(p2, v.w, a2.w);
      a3.x = fmaf(p3, v.x, a3.x); a3.y = fmaf(p3, v.y, a3.y);
      a3.z = fmaf(p3, v.z, a3.z); a3.w = fmaf(p3, v.w, a3.w);
    }
    *(float4*)&part[(g * 4 + 0) * DIM + d4] = a0;
    *(float4*)&part[(g * 4 + 1) * DIM + d4] = a1;
    *(float4*)&part[(g * 4 + 2) * DIM + d4] = a2;
    *(float4*)&part[(g * 4 + 3) * DIM + d4] = a3;
  }
  __syncthreads();

  // ---- epilogue: combine 4 group-partials, scale by 1/sum, store ----
  {
    const int rows[4] = {l0r, il, h0r, ih};
#pragma unroll
    for (int r = 0; r < 4; ++r) {
      const float o = (part[(0 * 4 + r) * DIM + t] + part[(1 * 4 + r) * DIM + t] +
                       part[(2 * 4 + r) * DIM + t] + part[(3 * 4 + r) * DIM + t]) * invs[r];
      out[(bS + rows[r]) * DIM + t] = o;
    }
  }
}

extern "C" void kernel_launch(void* const* d_in, const int* in_sizes, int n_in,
                              void* d_out, int out_size, void* d_ws, size_t ws_size,
                              hipStream_t stream) {
  const float* values = (const float*)d_in[0];
  const float* Wq     = (const float*)d_in[1];
  const float* Wv     = (const float*)d_in[2];
  const float* Vw     = (const float*)d_in[3];
  float* out = (float*)d_out;
  float* Qc  = (float*)d_ws;             // [BSZ][UN]  1 MB, pre-scaled by 2*log2e
  float* Vc  = Qc + (size_t)BSZ * UN;    // [UN][BSZ]  1 MB, pre-scaled by 2*log2e
  proj_kernel<<<dim3(BSZ / 4), 256, 0, stream>>>(values, Wq, Wv, Qc, Vc);
  attn_kernel<<<dim3(BSZ / 4), 256, 0, stream>>>(values, Qc, Vc, Vw, out);
}

// Round 3
// 128.487 us; speedup vs baseline: 1.1253x; 1.0737x over previous
//
#include <hip/hip_runtime.h>

// B=4, S=512, D=256, UNITS=128. out: [B,S,D] fp32.
#define SEQ 512
#define DIM 256
#define UN  128
#define BSZ 2048                       // B*S
#define CSC 2.8853900817779268f        // 2*log2(e): folded into Qc/Vc so exp2(Qc+Vc)=e^{2(q+v)}

// ---------------- proj: Qc = c*(values@Wq) [BSZ][UN], Vc = c*(values@Wv)^T [UN][BSZ] ----
__global__ __launch_bounds__(256) void proj_kernel(
    const float* __restrict__ values, const float* __restrict__ Wq,
    const float* __restrict__ Wv, float* __restrict__ Qc, float* __restrict__ Vc) {
  __shared__ float vsm[4 * DIM];
  const int t = threadIdx.x;
  const int r0 = blockIdx.x * 4;
  {
    const int row = t >> 6, c4 = (t & 63) * 4;
    *(float4*)&vsm[row * DIM + c4] = *(const float4*)(values + (r0 + row) * DIM + c4);
  }
  __syncthreads();
  const int half = t >> 7, u = t & 127;
  const float* __restrict__ W = half ? Wv : Wq;
  float acc[4] = {0.f, 0.f, 0.f, 0.f};
  for (int d = 0; d < DIM; d += 4) {
    const float w0 = W[(d + 0) * UN + u], w1 = W[(d + 1) * UN + u];
    const float w2 = W[(d + 2) * UN + u], w3 = W[(d + 3) * UN + u];
#pragma unroll
    for (int k = 0; k < 4; ++k) {
      const float4 v = *(const float4*)&vsm[k * DIM + d];
      acc[k] = fmaf(v.x, w0, acc[k]);
      acc[k] = fmaf(v.y, w1, acc[k]);
      acc[k] = fmaf(v.z, w2, acc[k]);
      acc[k] = fmaf(v.w, w3, acc[k]);
    }
  }
  if (!half) {
#pragma unroll
    for (int k = 0; k < 4; ++k) Qc[(r0 + k) * UN + u] = acc[k] * CSC;
  } else {
    const float4 o = make_float4(acc[0] * CSC, acc[1] * CSC, acc[2] * CSC, acc[3] * CSC);
    *(float4*)(Vc + u * BSZ + r0) = o;
  }
}

// ---------------- attn: block = (b, pair p) rows {p, S-1-p}; nested j-ranges ----------
// Low row i=p needs j in [0,i]; high row ihi=S-1-p needs j in [0,ihi] (superset).
// One Vc/values load serves both rows. 1024 blocks -> 4 blocks/CU, 16 waves/CU.
// score = -2*sdot + const (softmax shift-invariant), sdot = sum_u Vw_u/(e^{2(q+v)}+1).
__global__ __launch_bounds__(256, 4) void attn_kernel(
    const float* __restrict__ values, const float* __restrict__ Qc,
    const float* __restrict__ Vc, const float* __restrict__ Vw,
    float* __restrict__ out) {
  __shared__ float sc[2 * SEQ];      // [0..SEQ): low-row sdot->p, [SEQ..2SEQ): high-row
  __shared__ float part[8 * DIM];    // ctx partials: [4 j-groups][2 rows][DIM]
  __shared__ float invs[2];

  const int t = threadIdx.x;
  const int b = blockIdx.x >> 8, p = blockIdx.x & 255;
  const int bS = b * SEQ;
  const int i  = p;                  // low row, j in [0, i]
  const int ihi = SEQ - 1 - p;       // high row, j in [0, ihi], ihi >= 256
  const int jhi = ihi;

  const float* __restrict__ qlo = Qc + (bS + i) * UN;    // uniform -> s_load
  const float* __restrict__ qhi = Qc + (bS + ihi) * UN;
  const float* __restrict__ vcb = Vc + bS;

  // ---- phase A: scores. thread t handles j = t, t+256 (<= jhi). ----
  for (int j = t; j <= jhi; j += 256) {
    const float* __restrict__ vp = vcb + j;              // vp[u*BSZ], coalesced across t
    if (j <= i) {                                        // 2-row path (iter 0 only)
      float shi = 0.f, slo = 0.f;
#pragma unroll 4
      for (int u = 0; u < UN; ++u) {
        const float vc = vp[u * BSZ];
        const float ehi = __builtin_amdgcn_exp2f(qhi[u] + vc);  // inf-safe: rcp(inf)=0
        const float elo = __builtin_amdgcn_exp2f(qlo[u] + vc);
        const float w = Vw[u];
        shi = fmaf(w, __builtin_amdgcn_rcpf(ehi + 1.f), shi);
        slo = fmaf(w, __builtin_amdgcn_rcpf(elo + 1.f), slo);
      }
      sc[SEQ + j] = shi;
      sc[j] = slo;
    } else {                                             // 1-row path
      float shi = 0.f;
#pragma unroll 8
      for (int u = 0; u < UN; ++u) {
        const float vc = vp[u * BSZ];
        const float ehi = __builtin_amdgcn_exp2f(qhi[u] + vc);
        shi = fmaf(Vw[u], __builtin_amdgcn_rcpf(ehi + 1.f), shi);
      }
      sc[SEQ + j] = shi;
    }
  }
  __syncthreads();

  // ---- phase B: softmax. wave0 -> low row, wave1 -> high row (exact ranges). ----
  {
    const int w = t >> 6, l = t & 63;
    if (w < 2) {
      const int jmax = (w == 0) ? i : jhi;
      float* __restrict__ row = sc + w * SEQ;
      float m = 1e30f;                                   // min of sdot == max of score
      for (int j = l; j <= jmax; j += 64) m = fminf(m, row[j]);
#pragma unroll
      for (int o = 32; o; o >>= 1) m = fminf(m, __shfl_xor(m, o));
      float sum = 0.f;
      for (int j = l; j <= jmax; j += 64) {
        const float pr = __builtin_amdgcn_exp2f((m - row[j]) * CSC);
        row[j] = pr;
        sum += pr;
      }
#pragma unroll
      for (int o = 32; o; o >>= 1) sum += __shfl_xor(sum, o);
      if (l == 0) invs[w] = __builtin_amdgcn_rcpf(sum);
    }
  }
  __syncthreads();

  // ---- phase C: context. wave g takes j === g (mod 4); one values load, 2 rows. ----
  {
    const int g = t >> 6, d4 = (t & 63) * 4;
    float4 alo = make_float4(0.f, 0.f, 0.f, 0.f), ahi = alo;
    int j = g;
    for (; j <= i; j += 4) {                             // both rows
      const float plo = sc[j], phi = sc[SEQ + j];        // LDS broadcast
      const float4 v = *(const float4*)(values + (bS + j) * DIM + d4);
      alo.x = fmaf(plo, v.x, alo.x); alo.y = fmaf(plo, v.y, alo.y);
      alo.z = fmaf(plo, v.z, alo.z); alo.w = fmaf(plo, v.w, alo.w);
      ahi.x = fmaf(phi, v.x, ahi.x); ahi.y = fmaf(phi, v.y, ahi.y);
      ahi.z = fmaf(phi, v.z, ahi.z); ahi.w = fmaf(phi, v.w, ahi.w);
    }
    for (; j <= jhi; j += 4) {                           // high row only
      const float phi = sc[SEQ + j];
      const float4 v = *(const float4*)(values + (bS + j) * DIM + d4);
      ahi.x = fmaf(phi, v.x, ahi.x); ahi.y = fmaf(phi, v.y, ahi.y);
      ahi.z = fmaf(phi, v.z, ahi.z); ahi.w = fmaf(phi, v.w, ahi.w);
    }
    *(float4*)&part[(g * 2 + 0) * DIM + d4] = alo;
    *(float4*)&part[(g * 2 + 1) * DIM + d4] = ahi;
  }
  __syncthreads();

  // ---- epilogue: combine 4 group-partials per row, scale, store ----
  {
    const float olo = (part[0 * DIM + t] + part[2 * DIM + t] +
                       part[4 * DIM + t] + part[6 * DIM + t]) * invs[0];
    const float ohi = (part[1 * DIM + t] + part[3 * DIM + t] +
                       part[5 * DIM + t] + part[7 * DIM + t]) * invs[1];
    out[(bS + i) * DIM + t] = olo;
    out[(bS + ihi) * DIM + t] = ohi;
  }
}

extern "C" void kernel_launch(void* const* d_in, const int* in_sizes, int n_in,
                              void* d_out, int out_size, void* d_ws, size_t ws_size,
                              hipStream_t stream) {
  const float* values = (const float*)d_in[0];
  const float* Wq     = (const float*)d_in[1];
  const float* Wv     = (const float*)d_in[2];
  const float* Vw     = (const float*)d_in[3];
  float* out = (float*)d_out;
  float* Qc  = (float*)d_ws;             // [BSZ][UN]  1 MB, pre-scaled by 2*log2e
  float* Vc  = Qc + (size_t)BSZ * UN;    // [UN][BSZ]  1 MB, pre-scaled by 2*log2e
  proj_kernel<<<dim3(BSZ / 4), 256, 0, stream>>>(values, Wq, Wv, Qc, Vc);
  attn_kernel<<<dim3(4 * 256), 256, 0, stream>>>(values, Qc, Vc, Vw, out);
}

// Round 4
// 118.103 us; speedup vs baseline: 1.2243x; 1.0879x over previous
//
#include <hip/hip_runtime.h>
#include <hip/hip_fp16.h>

// B=4, S=512, D=256, UNITS=128. out: [B,S,D] fp32.
#define SEQ 512
#define DIM 256
#define UN  128
#define BSZ 2048                       // B*S
#define CSC 2.8853900817779268f        // 2*log2(e): folded into Qc/Vc so exp2(Qc+Vc)=e^{2(q+v)}

struct h8 { __half2 a, b, c, d; };     // 16B = 8 f16

// ---- proj: Qc = c*(values@Wq) [BSZ][UN], Vc = c*(values@Wv)^T [UN][BSZ], Vf16 = f16(values)
__global__ __launch_bounds__(256) void proj_kernel(
    const float* __restrict__ values, const float* __restrict__ Wq,
    const float* __restrict__ Wv, float* __restrict__ Qc, float* __restrict__ Vc,
    __half* __restrict__ Vf16) {
  __shared__ float vsm[4 * DIM];
  const int t = threadIdx.x;
  const int r0 = blockIdx.x * 4;
  {
    const int row = t >> 6, c4 = (t & 63) * 4;
    const float4 v = *(const float4*)(values + (r0 + row) * DIM + c4);
    *(float4*)&vsm[row * DIM + c4] = v;
    __half2* vf = (__half2*)(Vf16 + (r0 + row) * DIM + c4);
    vf[0] = __floats2half2_rn(v.x, v.y);
    vf[1] = __floats2half2_rn(v.z, v.w);
  }
  __syncthreads();
  const int half = t >> 7, u = t & 127;
  const float* __restrict__ W = half ? Wv : Wq;
  float acc[4] = {0.f, 0.f, 0.f, 0.f};
  for (int d = 0; d < DIM; d += 4) {
    const float w0 = W[(d + 0) * UN + u], w1 = W[(d + 1) * UN + u];
    const float w2 = W[(d + 2) * UN + u], w3 = W[(d + 3) * UN + u];
#pragma unroll
    for (int k = 0; k < 4; ++k) {
      const float4 v = *(const float4*)&vsm[k * DIM + d];
      acc[k] = fmaf(v.x, w0, acc[k]);
      acc[k] = fmaf(v.y, w1, acc[k]);
      acc[k] = fmaf(v.z, w2, acc[k]);
      acc[k] = fmaf(v.w, w3, acc[k]);
    }
  }
  if (!half) {
#pragma unroll
    for (int k = 0; k < 4; ++k) Qc[(r0 + k) * UN + u] = acc[k] * CSC;
  } else {
    const float4 o = make_float4(acc[0] * CSC, acc[1] * CSC, acc[2] * CSC, acc[3] * CSC);
    *(float4*)(Vc + u * BSZ + r0) = o;
  }
}

// ---- attn: block = (b, pair p) rows {p, S-1-p}. i + jhi = 511 -> constant work/block.
__global__ __launch_bounds__(256, 4) void attn_kernel(
    const __half* __restrict__ Vf16, const float* __restrict__ Qc,
    const float* __restrict__ Vc, const float* __restrict__ Vw,
    float* __restrict__ out) {
  __shared__ float sc[2 * SEQ];     // u-half-0 sdot partials -> probs. [lo | hi]
  __shared__ float scp[2 * SEQ];    // u-half-1 sdot partials
  __shared__ float part[8 * DIM];   // ctx partials: [wave g][2 rows][DIM]
  __shared__ float invs[2];

  const int t = threadIdx.x;
  const int b = blockIdx.x >> 8, p = blockIdx.x & 255;
  const int bS = b * SEQ;
  const int i = p;                  // low row: j in [0, i]
  const int ihi = SEQ - 1 - p;      // high row: j in [0, ihi], ihi >= 256
  const int jhi = ihi;

  const float* __restrict__ qlo = Qc + (bS + i) * UN;    // uniform -> s_load
  const float* __restrict__ qhi = Qc + (bS + ihi) * UN;

  // ---- phase A: thread owns j-quad (16B Vc load) x u-half. 8 indep exp chains/iter.
  {
    const int qd = t & 127;         // j = 4qd .. 4qd+3
    const int u0 = (t >> 7) << 6;   // u-half: [0,64) or [64,128)
    const int jb = qd << 2;
    float* __restrict__ so = (t >> 7) ? scp : sc;
    const float* __restrict__ vq = Vc + bS + jb;
    if ((t & 64) == 0) {            // waves 0,2: jb < 256 -> hi always, lo unconditional
      float h0=0.f,h1=0.f,h2=0.f,h3=0.f,l0=0.f,l1=0.f,l2=0.f,l3=0.f;
#pragma unroll 2
      for (int u = u0; u < u0 + 64; ++u) {
        const float4 vc = *(const float4*)(vq + (size_t)u * BSZ);
        const float qh = qhi[u], ql = qlo[u], w = Vw[u];
        h0 = fmaf(w, __builtin_amdgcn_rcpf(__builtin_amdgcn_exp2f(qh + vc.x) + 1.f), h0);
        h1 = fmaf(w, __builtin_amdgcn_rcpf(__builtin_amdgcn_exp2f(qh + vc.y) + 1.f), h1);
        h2 = fmaf(w, __builtin_amdgcn_rcpf(__builtin_amdgcn_exp2f(qh + vc.z) + 1.f), h2);
        h3 = fmaf(w, __builtin_amdgcn_rcpf(__builtin_amdgcn_exp2f(qh + vc.w) + 1.f), h3);
        l0 = fmaf(w, __builtin_amdgcn_rcpf(__builtin_amdgcn_exp2f(ql + vc.x) + 1.f), l0);
        l1 = fmaf(w, __builtin_amdgcn_rcpf(__builtin_amdgcn_exp2f(ql + vc.y) + 1.f), l1);
        l2 = fmaf(w, __builtin_amdgcn_rcpf(__builtin_amdgcn_exp2f(ql + vc.z) + 1.f), l2);
        l3 = fmaf(w, __builtin_amdgcn_rcpf(__builtin_amdgcn_exp2f(ql + vc.w) + 1.f), l3);
      }
      *(float4*)&so[SEQ + jb] = make_float4(h0, h1, h2, h3);
      *(float4*)&so[jb]       = make_float4(l0, l1, l2, l3);  // slots > i never read
    } else if (jb <= jhi) {         // waves 1,3: jb >= 256 -> hi only
      float h0=0.f,h1=0.f,h2=0.f,h3=0.f;
#pragma unroll 4
      for (int u = u0; u < u0 + 64; ++u) {
        const float4 vc = *(const float4*)(vq + (size_t)u * BSZ);
        const float qh = qhi[u], w = Vw[u];
        h0 = fmaf(w, __builtin_amdgcn_rcpf(__builtin_amdgcn_exp2f(qh + vc.x) + 1.f), h0);
        h1 = fmaf(w, __builtin_amdgcn_rcpf(__builtin_amdgcn_exp2f(qh + vc.y) + 1.f), h1);
        h2 = fmaf(w, __builtin_amdgcn_rcpf(__builtin_amdgcn_exp2f(qh + vc.z) + 1.f), h2);
        h3 = fmaf(w, __builtin_amdgcn_rcpf(__builtin_amdgcn_exp2f(qh + vc.w) + 1.f), h3);
      }
      *(float4*)&so[SEQ + jb] = make_float4(h0, h1, h2, h3);  // slots > jhi never read
    }
  }
  __syncthreads();

  // ---- phase B: softmax, wave0 -> low row, wave1 -> high row, exact ranges ----
  {
    const int w = t >> 6, l = t & 63;
    if (w < 2) {
      const int jmax = (w == 0) ? i : jhi;
      float* __restrict__ r0p = sc + w * SEQ;
      const float* __restrict__ r1p = scp + w * SEQ;
      float m = 1e30f;                           // min sdot == max score
      for (int j = l; j <= jmax; j += 64) m = fminf(m, r0p[j] + r1p[j]);
#pragma unroll
      for (int o = 32; o; o >>= 1) m = fminf(m, __shfl_xor(m, o));
      float sum = 0.f;
      for (int j = l; j <= jmax; j += 64) {
        const float pr = __builtin_amdgcn_exp2f((m - (r0p[j] + r1p[j])) * CSC);
        r0p[j] = pr;
        sum += pr;
      }
#pragma unroll
      for (int o = 32; o; o >>= 1) sum += __shfl_xor(sum, o);
      if (l == 0) invs[w] = __builtin_amdgcn_rcpf(sum);
    }
  }
  __syncthreads();

  // ---- phase C: f16 values, lane covers 8 d; wave g + lane-half jo -> j === 2g+jo (mod 8)
  {
    const int g = t >> 6, l = t & 63;
    const int jo = l >> 5, d8 = (l & 31) << 3;
    float alo[8], ahi[8];
#pragma unroll
    for (int k = 0; k < 8; ++k) { alo[k] = 0.f; ahi[k] = 0.f; }
    int j = 2 * g + jo;
    for (; j <= i; j += 8) {                      // both rows share the load
      const float plo = sc[j], phi = sc[SEQ + j];
      const h8 v = *(const h8*)(Vf16 + (size_t)(bS + j) * DIM + d8);
      const float2 f0 = __half22float2(v.a), f1 = __half22float2(v.b);
      const float2 f2 = __half22float2(v.c), f3 = __half22float2(v.d);
      alo[0] = fmaf(plo, f0.x, alo[0]); alo[1] = fmaf(plo, f0.y, alo[1]);
      alo[2] = fmaf(plo, f1.x, alo[2]); alo[3] = fmaf(plo, f1.y, alo[3]);
      alo[4] = fmaf(plo, f2.x, alo[4]); alo[5] = fmaf(plo, f2.y, alo[5]);
      alo[6] = fmaf(plo, f3.x, alo[6]); alo[7] = fmaf(plo, f3.y, alo[7]);
      ahi[0] = fmaf(phi, f0.x, ahi[0]); ahi[1] = fmaf(phi, f0.y, ahi[1]);
      ahi[2] = fmaf(phi, f1.x, ahi[2]); ahi[3] = fmaf(phi, f1.y, ahi[3]);
      ahi[4] = fmaf(phi, f2.x, ahi[4]); ahi[5] = fmaf(phi, f2.y, ahi[5]);
      ahi[6] = fmaf(phi, f3.x, ahi[6]); ahi[7] = fmaf(phi, f3.y, ahi[7]);
    }
    for (; j <= jhi; j += 8) {                    // high row only
      const float phi = sc[SEQ + j];
      const h8 v = *(const h8*)(Vf16 + (size_t)(bS + j) * DIM + d8);
      const float2 f0 = __half22float2(v.a), f1 = __half22float2(v.b);
      const float2 f2 = __half22float2(v.c), f3 = __half22float2(v.d);
      ahi[0] = fmaf(phi, f0.x, ahi[0]); ahi[1] = fmaf(phi, f0.y, ahi[1]);
      ahi[2] = fmaf(phi, f1.x, ahi[2]); ahi[3] = fmaf(phi, f1.y, ahi[3]);
      ahi[4] = fmaf(phi, f2.x, ahi[4]); ahi[5] = fmaf(phi, f2.y, ahi[5]);
      ahi[6] = fmaf(phi, f3.x, ahi[6]); ahi[7] = fmaf(phi, f3.y, ahi[7]);
    }
#pragma unroll
    for (int k = 0; k < 8; ++k) {                 // fold jo halves (lanes l, l+32)
      alo[k] += __shfl_xor(alo[k], 32);
      ahi[k] += __shfl_xor(ahi[k], 32);
    }
    if (jo == 0) {
      float* __restrict__ plo_ = &part[(g * 2 + 0) * DIM + d8];
      float* __restrict__ phi_ = &part[(g * 2 + 1) * DIM + d8];
      *(float4*)(plo_ + 0) = make_float4(alo[0], alo[1], alo[2], alo[3]);
      *(float4*)(plo_ + 4) = make_float4(alo[4], alo[5], alo[6], alo[7]);
      *(float4*)(phi_ + 0) = make_float4(ahi[0], ahi[1], ahi[2], ahi[3]);
      *(float4*)(phi_ + 4) = make_float4(ahi[4], ahi[5], ahi[6], ahi[7]);
    }
  }
  __syncthreads();

  // ---- epilogue ----
  {
    const float olo = (part[0 * DIM + t] + part[2 * DIM + t] +
                       part[4 * DIM + t] + part[6 * DIM + t]) * invs[0];
    const float ohi = (part[1 * DIM + t] + part[3 * DIM + t] +
                       part[5 * DIM + t] + part[7 * DIM + t]) * invs[1];
    out[(bS + i) * DIM + t] = olo;
    out[(bS + ihi) * DIM + t] = ohi;
  }
}

extern "C" void kernel_launch(void* const* d_in, const int* in_sizes, int n_in,
                              void* d_out, int out_size, void* d_ws, size_t ws_size,
                              hipStream_t stream) {
  const float* values = (const float*)d_in[0];
  const float* Wq     = (const float*)d_in[1];
  const float* Wv     = (const float*)d_in[2];
  const float* Vw     = (const float*)d_in[3];
  float* out = (float*)d_out;
  float* Qc   = (float*)d_ws;                    // [BSZ][UN]  1 MB
  float* Vc   = Qc + (size_t)BSZ * UN;           // [UN][BSZ]  1 MB
  __half* Vf16 = (__half*)(Vc + (size_t)BSZ * UN); // [BSZ][DIM] 1 MB
  proj_kernel<<<dim3(BSZ / 4), 256, 0, stream>>>(values, Wq, Wv, Qc, Vc, Vf16);
  attn_kernel<<<dim3(4 * 256), 256, 0, stream>>>(Vf16, Qc, Vc, Vw, out);
}

// Round 5
// 105.357 us; speedup vs baseline: 1.3724x; 1.1210x over previous
//
#include <hip/hip_runtime.h>
#include <hip/hip_fp16.h>

// B=4, S=512, D=256, UNITS=128. out: [B,S,D] fp32.
#define SEQ 512
#define DIM 256
#define UN  128
#define BSZ 2048                       // B*S
#define CSC 2.8853900817779268f        // 2*log2(e)

struct h8 { __half2 a, b, c, d; };     // 16B = 8 f16

static __device__ __forceinline__ unsigned short f2bf(float x) {  // RNE, x>0 finite
  unsigned u = __float_as_uint(x);
  u += 0x7FFF + ((u >> 16) & 1);
  return (unsigned short)(u >> 16);
}
static __device__ __forceinline__ float bf2f(unsigned short s) {
  return __uint_as_float((unsigned)s << 16);
}

// ---- proj: Eq = exp2(CSC*(values@Wq)) [BSZ][UN] fp32,
//            Ev = bf16(exp2(CSC*(values@Wv)))^T [UN][BSZ],
//            Vf16 = f16(values) [BSZ][DIM]
__global__ __launch_bounds__(256) void proj_kernel(
    const float* __restrict__ values, const float* __restrict__ Wq,
    const float* __restrict__ Wv, float* __restrict__ Eq,
    unsigned short* __restrict__ Ev, __half* __restrict__ Vf16) {
  __shared__ float vsm[4 * DIM];
  const int t = threadIdx.x;
  const int r0 = blockIdx.x * 4;
  {
    const int row = t >> 6, c4 = (t & 63) * 4;
    const float4 v = *(const float4*)(values + (r0 + row) * DIM + c4);
    *(float4*)&vsm[row * DIM + c4] = v;
    __half2* vf = (__half2*)(Vf16 + (r0 + row) * DIM + c4);
    vf[0] = __floats2half2_rn(v.x, v.y);
    vf[1] = __floats2half2_rn(v.z, v.w);
  }
  __syncthreads();
  const int half = t >> 7, u = t & 127;
  const float* __restrict__ W = half ? Wv : Wq;
  float acc[4] = {0.f, 0.f, 0.f, 0.f};
  for (int d = 0; d < DIM; d += 4) {
    const float w0 = W[(d + 0) * UN + u], w1 = W[(d + 1) * UN + u];
    const float w2 = W[(d + 2) * UN + u], w3 = W[(d + 3) * UN + u];
#pragma unroll
    for (int k = 0; k < 4; ++k) {
      const float4 v = *(const float4*)&vsm[k * DIM + d];
      acc[k] = fmaf(v.x, w0, acc[k]);
      acc[k] = fmaf(v.y, w1, acc[k]);
      acc[k] = fmaf(v.z, w2, acc[k]);
      acc[k] = fmaf(v.w, w3, acc[k]);
    }
  }
  if (!half) {
#pragma unroll
    for (int k = 0; k < 4; ++k)
      Eq[(r0 + k) * UN + u] = __builtin_amdgcn_exp2f(acc[k] * CSC);
  } else {
    ushort4 o;
    o.x = f2bf(__builtin_amdgcn_exp2f(acc[0] * CSC));
    o.y = f2bf(__builtin_amdgcn_exp2f(acc[1] * CSC));
    o.z = f2bf(__builtin_amdgcn_exp2f(acc[2] * CSC));
    o.w = f2bf(__builtin_amdgcn_exp2f(acc[3] * CSC));
    *(ushort4*)(Ev + (size_t)u * BSZ + r0) = o;   // 8B aligned (r0%4==0)
  }
}

// ---- attn: block = (b, pair p), rows {p, S-1-p}; i + jhi = 511 -> constant work.
// tanh eval: d = fma(Eq, Ev, 1); term = Vw * rcp(d).  1 trans + 2 VALU per eval.
__global__ __launch_bounds__(256, 4) void attn_kernel(
    const __half* __restrict__ Vf16, const float* __restrict__ Eq,
    const unsigned short* __restrict__ Ev, const float* __restrict__ Vw,
    float* __restrict__ out) {
  __shared__ float sc[2 * SEQ];     // u-half-0 sdot partials -> probs. [lo | hi]
  __shared__ float scp[2 * SEQ];    // u-half-1 sdot partials
  __shared__ float part[8 * DIM];   // ctx partials: [wave g][2 rows][DIM]
  __shared__ float invs[2];

  const int t = threadIdx.x;
  const int b = blockIdx.x >> 8, p = blockIdx.x & 255;
  const int bS = b * SEQ;
  const int i = p;                  // low row: j in [0, i]
  const int ihi = SEQ - 1 - p;      // high row: j in [0, ihi], ihi >= 256
  const int jhi = ihi;

  const float* __restrict__ eql = Eq + (bS + i) * UN;    // uniform -> s_load
  const float* __restrict__ eqh = Eq + (bS + ihi) * UN;

  // ---- phase A: thread owns j-quad (8B bf16 Ev load) x u-half ----
  {
    const int qd = t & 127, jb = qd << 2;
    const int u0 = (t >> 7) << 6;
    float* __restrict__ so = (t >> 7) ? scp : sc;
    const unsigned short* __restrict__ evp = Ev + (size_t)u0 * BSZ + bS + jb;
    if ((t & 64) == 0) {            // waves 0,2: jb < 256 -> dual row
      float h0=0.f,h1=0.f,h2=0.f,h3=0.f,l0=0.f,l1=0.f,l2=0.f,l3=0.f;
      ushort4 ec = *(const ushort4*)evp;   // prefetch k=0
#pragma unroll 4
      for (int k = 0; k < 64; ++k) {
        // prefetch next u row; k=63 reads one row past -> lands in Vf16 region (valid mem)
        const ushort4 en = *(const ushort4*)(evp + (size_t)(k + 1) * BSZ);
        const float qh = eqh[u0 + k], ql = eql[u0 + k], w = Vw[u0 + k];
        const float e0 = bf2f(ec.x), e1 = bf2f(ec.y), e2 = bf2f(ec.z), e3 = bf2f(ec.w);
        h0 = fmaf(w, __builtin_amdgcn_rcpf(fmaf(qh, e0, 1.f)), h0);
        h1 = fmaf(w, __builtin_amdgcn_rcpf(fmaf(qh, e1, 1.f)), h1);
        h2 = fmaf(w, __builtin_amdgcn_rcpf(fmaf(qh, e2, 1.f)), h2);
        h3 = fmaf(w, __builtin_amdgcn_rcpf(fmaf(qh, e3, 1.f)), h3);
        l0 = fmaf(w, __builtin_amdgcn_rcpf(fmaf(ql, e0, 1.f)), l0);
        l1 = fmaf(w, __builtin_amdgcn_rcpf(fmaf(ql, e1, 1.f)), l1);
        l2 = fmaf(w, __builtin_amdgcn_rcpf(fmaf(ql, e2, 1.f)), l2);
        l3 = fmaf(w, __builtin_amdgcn_rcpf(fmaf(ql, e3, 1.f)), l3);
        ec = en;
      }
      *(float4*)&so[SEQ + jb] = make_float4(h0, h1, h2, h3);
      *(float4*)&so[jb]       = make_float4(l0, l1, l2, l3);  // slots > i never read
    } else if (jb <= jhi) {         // waves 1,3: jb >= 256 -> hi only
      float h0=0.f,h1=0.f,h2=0.f,h3=0.f;
      ushort4 ec = *(const ushort4*)evp;
#pragma unroll 4
      for (int k = 0; k < 64; ++k) {
        const ushort4 en = *(const ushort4*)(evp + (size_t)(k + 1) * BSZ);
        const float qh = eqh[u0 + k], w = Vw[u0 + k];
        h0 = fmaf(w, __builtin_amdgcn_rcpf(fmaf(qh, bf2f(ec.x), 1.f)), h0);
        h1 = fmaf(w, __builtin_amdgcn_rcpf(fmaf(qh, bf2f(ec.y), 1.f)), h1);
        h2 = fmaf(w, __builtin_amdgcn_rcpf(fmaf(qh, bf2f(ec.z), 1.f)), h2);
        h3 = fmaf(w, __builtin_amdgcn_rcpf(fmaf(qh, bf2f(ec.w), 1.f)), h3);
        ec = en;
      }
      *(float4*)&so[SEQ + jb] = make_float4(h0, h1, h2, h3);  // slots > jhi never read
    }
  }
  __syncthreads();

  // ---- phase B: softmax, wave0 -> low row, wave1 -> high row, exact ranges ----
  {
    const int w = t >> 6, l = t & 63;
    if (w < 2) {
      const int jmax = (w == 0) ? i : jhi;
      float* __restrict__ r0p = sc + w * SEQ;
      const float* __restrict__ r1p = scp + w * SEQ;
      float m = 1e30f;                           // min sdot == max score
      for (int j = l; j <= jmax; j += 64) m = fminf(m, r0p[j] + r1p[j]);
#pragma unroll
      for (int o = 32; o; o >>= 1) m = fminf(m, __shfl_xor(m, o));
      float sum = 0.f;
      for (int j = l; j <= jmax; j += 64) {
        const float pr = __builtin_amdgcn_exp2f((m - (r0p[j] + r1p[j])) * CSC);
        r0p[j] = pr;
        sum += pr;
      }
#pragma unroll
      for (int o = 32; o; o >>= 1) sum += __shfl_xor(sum, o);
      if (l == 0) invs[w] = __builtin_amdgcn_rcpf(sum);
    }
  }
  __syncthreads();

  // ---- phase C: f16 values, lane covers 8 d; wave g + lane-half jo -> j === 2g+jo (mod 8)
  {
    const int g = t >> 6, l = t & 63;
    const int jo = l >> 5, d8 = (l & 31) << 3;
    float alo[8], ahi[8];
#pragma unroll
    for (int k = 0; k < 8; ++k) { alo[k] = 0.f; ahi[k] = 0.f; }
    int j = 2 * g + jo;                           // j0 <= 7 <= jhi always
    h8 vc = *(const h8*)(Vf16 + (size_t)(bS + j) * DIM + d8);
    for (; j <= i; j += 8) {                      // both rows share the load
      const int jn = (j + 8 <= jhi) ? j + 8 : jhi;          // clamp: no OOB
      const h8 vn = *(const h8*)(Vf16 + (size_t)(bS + jn) * DIM + d8);
      const float plo = sc[j], phi = sc[SEQ + j];
      const float2 f0 = __half22float2(vc.a), f1 = __half22float2(vc.b);
      const float2 f2 = __half22float2(vc.c), f3 = __half22float2(vc.d);
      alo[0] = fmaf(plo, f0.x, alo[0]); alo[1] = fmaf(plo, f0.y, alo[1]);
      alo[2] = fmaf(plo, f1.x, alo[2]); alo[3] = fmaf(plo, f1.y, alo[3]);
      alo[4] = fmaf(plo, f2.x, alo[4]); alo[5] = fmaf(plo, f2.y, alo[5]);
      alo[6] = fmaf(plo, f3.x, alo[6]); alo[7] = fmaf(plo, f3.y, alo[7]);
      ahi[0] = fmaf(phi, f0.x, ahi[0]); ahi[1] = fmaf(phi, f0.y, ahi[1]);
      ahi[2] = fmaf(phi, f1.x, ahi[2]); ahi[3] = fmaf(phi, f1.y, ahi[3]);
      ahi[4] = fmaf(phi, f2.x, ahi[4]); ahi[5] = fmaf(phi, f2.y, ahi[5]);
      ahi[6] = fmaf(phi, f3.x, ahi[6]); ahi[7] = fmaf(phi, f3.y, ahi[7]);
      vc = vn;
    }
    for (; j <= jhi; j += 8) {                    // high row only
      const int jn = (j + 8 <= jhi) ? j + 8 : jhi;
      const h8 vn = *(const h8*)(Vf16 + (size_t)(bS + jn) * DIM + d8);
      const float phi = sc[SEQ + j];
      const float2 f0 = __half22float2(vc.a), f1 = __half22float2(vc.b);
      const float2 f2 = __half22float2(vc.c), f3 = __half22float2(vc.d);
      ahi[0] = fmaf(phi, f0.x, ahi[0]); ahi[1] = fmaf(phi, f0.y, ahi[1]);
      ahi[2] = fmaf(phi, f1.x, ahi[2]); ahi[3] = fmaf(phi, f1.y, ahi[3]);
      ahi[4] = fmaf(phi, f2.x, ahi[4]); ahi[5] = fmaf(phi, f2.y, ahi[5]);
      ahi[6] = fmaf(phi, f3.x, ahi[6]); ahi[7] = fmaf(phi, f3.y, ahi[7]);
      vc = vn;
    }
#pragma unroll
    for (int k = 0; k < 8; ++k) {                 // fold jo halves (lanes l, l+32)
      alo[k] += __shfl_xor(alo[k], 32);
      ahi[k] += __shfl_xor(ahi[k], 32);
    }
    if (jo == 0) {
      float* __restrict__ plo_ = &part[(g * 2 + 0) * DIM + d8];
      float* __restrict__ phi_ = &part[(g * 2 + 1) * DIM + d8];
      *(float4*)(plo_ + 0) = make_float4(alo[0], alo[1], alo[2], alo[3]);
      *(float4*)(plo_ + 4) = make_float4(alo[4], alo[5], alo[6], alo[7]);
      *(float4*)(phi_ + 0) = make_float4(ahi[0], ahi[1], ahi[2], ahi[3]);
      *(float4*)(phi_ + 4) = make_float4(ahi[4], ahi[5], ahi[6], ahi[7]);
    }
  }
  __syncthreads();

  // ---- epilogue ----
  {
    const float olo = (part[0 * DIM + t] + part[2 * DIM + t] +
                       part[4 * DIM + t] + part[6 * DIM + t]) * invs[0];
    const float ohi = (part[1 * DIM + t] + part[3 * DIM + t] +
                       part[5 * DIM + t] + part[7 * DIM + t]) * invs[1];
    out[(bS + i) * DIM + t] = olo;
    out[(bS + ihi) * DIM + t] = ohi;
  }
}

extern "C" void kernel_launch(void* const* d_in, const int* in_sizes, int n_in,
                              void* d_out, int out_size, void* d_ws, size_t ws_size,
                              hipStream_t stream) {
  const float* values = (const float*)d_in[0];
  const float* Wq     = (const float*)d_in[1];
  const float* Wv     = (const float*)d_in[2];
  const float* Vw     = (const float*)d_in[3];
  float* out = (float*)d_out;
  float* Eq = (float*)d_ws;                            // [BSZ][UN] fp32, 1 MB
  unsigned short* Ev = (unsigned short*)(Eq + (size_t)BSZ * UN);  // [UN][BSZ] bf16, 512 KB
  __half* Vf16 = (__half*)(Ev + (size_t)UN * BSZ);     // [BSZ][DIM] f16, 1 MB
  proj_kernel<<<dim3(BSZ / 4), 256, 0, stream>>>(values, Wq, Wv, Eq, Ev, Vf16);
  attn_kernel<<<dim3(4 * 256), 256, 0, stream>>>(Vf16, Eq, Ev, Vw, out);
}